// Round 8
// baseline (187.295 us; speedup 1.0000x reference)
//
#include <hip/hip_runtime.h>
#include <math.h>

// Problem constants
#define BB    4
#define CIN   256
#define HH    64
#define WWID  64
#define COUT  256
#define KKS   3
#define K2    9
#define PADV  1
#define HWSZ  4096
#define GROUPS 32
#define CPG   8
#define EPSV  1e-5f
#define ROWB  4608          // K2*CIN * sizeof(bf16)
#define NKC   36            // K chunks of 64

typedef __attribute__((ext_vector_type(8))) short bf16x8;
typedef __attribute__((ext_vector_type(4))) float f32x4;

#define GLOAD_LDS16(g, l) \
    __builtin_amdgcn_global_load_lds((const __attribute__((address_space(1))) unsigned int*)(g), \
                                     (__attribute__((address_space(3))) unsigned int*)(l), 16, 0, 0)

__device__ __forceinline__ unsigned short f2bf(float f) {
    unsigned u = __float_as_uint(f);
    u = (u + 0x7fffu + ((u >> 16) & 1u)) >> 16;   // RNE
    return (unsigned short)u;
}
__device__ __forceinline__ float bflo(unsigned q) { return __uint_as_float(q << 16); }
__device__ __forceinline__ float bfhi(unsigned q) { return __uint_as_float(q & 0xffff0000u); }
__device__ __forceinline__ float aload(const float* p) {
    return __hip_atomic_load(p, __ATOMIC_RELAXED, __HIP_MEMORY_SCOPE_AGENT);
}
__device__ __forceinline__ void fma8(float* f, float w, uint4 q) {
    f[0] += w * bflo(q.x); f[1] += w * bfhi(q.x);
    f[2] += w * bflo(q.y); f[3] += w * bfhi(q.y);
    f[4] += w * bflo(q.z); f[5] += w * bfhi(q.z);
    f[6] += w * bflo(q.w); f[7] += w * bfhi(q.w);
}

// ---------------------------------------------------------------------------
// k_pre: grid (129, 8, 4).
//  bx<128 : x NCHW -> NHWC bf16 tile transpose
//  bx==128: weight [Cout][Cin][K2] -> bf16 [co][k2][q][chunk c ^ (co&7)]
//           block (128,0,0) zeroes gstat + spin counter (ALL 264 floats —
//           R6 hang: t<264 test in a 256-thread block left cnt poisoned)
// ---------------------------------------------------------------------------
__global__ __launch_bounds__(256)
void k_pre(const float* __restrict__ x, unsigned short* __restrict__ xh,
           const float* __restrict__ w, unsigned short* __restrict__ wtb,
           float* __restrict__ gstat) {
    int t = threadIdx.x;
    if (blockIdx.x < 128) {
        __shared__ float tile[32][33];
        int hw0 = blockIdx.x * 32;
        int c0  = blockIdx.y * 32;
        int b   = blockIdx.z;
        int tx = t & 31, ty = t >> 5;
        const float* xp = x + (size_t)b * CIN * HWSZ;
        #pragma unroll
        for (int i = 0; i < 4; i++)
            tile[ty + i * 8][tx] = xp[(c0 + ty + i * 8) * HWSZ + hw0 + tx];
        __syncthreads();
        int j = t >> 3, cq = t & 7;      // row hw0+j, 4 channels cq*4..
        union { unsigned short s[4]; uint2 d; } pk;
        #pragma unroll
        for (int k = 0; k < 4; k++) pk.s[k] = f2bf(tile[cq * 4 + k][j]);
        *(uint2*)((char*)xh + ((size_t)b * HWSZ * CIN + (size_t)(hw0 + j) * CIN + c0 + cq * 4) * 2) = pk.d;
    } else {
        if (blockIdx.y == 0 && blockIdx.z == 0)
            for (int i = t; i < BB * GROUPS * 2 + 8; i += 256) gstat[i] = 0.f;
        int idx = (blockIdx.y * 4 + blockIdx.z) * 256 + t;   // [0,8192)
        int co = idx >> 5, c8 = idx & 31;
        int cin0 = c8 * 8;
        int q = c8 >> 3, c = c8 & 7;
        int pc = c ^ (co & 7);
        for (int k2 = 0; k2 < K2; k2++) {
            union { unsigned short s[8]; uint4 qq; } pk;
            #pragma unroll
            for (int j = 0; j < 8; j++)
                pk.s[j] = f2bf(w[(co * CIN + cin0 + j) * K2 + k2]);
            int phys = co * ROWB + k2 * 512 + q * 128 + pc * 16;
            *(uint4*)((char*)wtb + phys) = pk.qq;
        }
    }
}

// ---------------------------------------------------------------------------
// k_mega: full fused DCNv2 + GN + ReLU.
// Grid 256 blocks x 512 thr (1 block/CU, coop-launched for residency).
// Per block: M=256 (all couts) x N=64 pixels, K=2304 in 36 chunks of 64.
// Pipelined single-barrier K-loop: [pack Bs(kc)] barrier [issue gathers(kc+1)
// + A-glds(kc+1)] [MFMA(kc)]. Sampling not duplicated.
// GN: LDS stats -> global atomics -> manual spin barrier -> finalize in-reg.
// ---------------------------------------------------------------------------
__global__ __launch_bounds__(512, 2)
void k_mega(const unsigned short* __restrict__ wtb, const unsigned short* __restrict__ xh,
            const float* __restrict__ offset, const float* __restrict__ mask,
            const float* __restrict__ bias, const float* __restrict__ gamma,
            const float* __restrict__ beta, float* __restrict__ out,
            float* __restrict__ gstat, int* __restrict__ cnt) {
    __shared__ unsigned short As[2][256 * 64];   // 2 x 32 KB
    __shared__ unsigned short Bs[2][64 * 64];    // 2 x 8 KB
    __shared__ int   cidx[64 * K2 * 4];          // 9 KB
    __shared__ float cwgt[64 * K2 * 4];          // 9 KB
    __shared__ float gs[32], gss[32], gmu[32], grstd[32];

    int bid = blockIdx.x;
    int strip = ((bid & 7) << 5) | (bid >> 3);   // XCD-contiguous pixel strips
    int b = strip >> 6;
    int hwbase = (strip & 63) * 64;
    int t = threadIdx.x;
    int w = t >> 6, l = t & 63;
    int r16 = l & 15, half = l >> 4;
    int wm = w & 3, wn = w >> 2;
    int gb = half >> 1;

    if (t < 32) { gs[t] = 0.f; gss[t] = 0.f; }

    // ---- corner prep: 576 (px,k2) pairs
    for (int i = t; i < 64 * K2; i += 512) {
        int px = i / K2, k2 = i - px * K2;
        int hw = hwbase + px;
        int ho = hw >> 6, wo = hw & 63;
        int ky = k2 / KKS, kx = k2 - ky * KKS;
        float dy = offset[((b * (2 * K2) + k2 * 2 + 0) * HWSZ) + hw];
        float dx = offset[((b * (2 * K2) + k2 * 2 + 1) * HWSZ) + hw];
        float m  = mask[(b * K2 + k2) * HWSZ + hw];
        float y  = (float)(ky + ho - PADV) + dy;
        float xc = (float)(kx + wo - PADV) + dx;
        float y0f = floorf(y), x0f = floorf(xc);
        float fy = y - y0f, fx = xc - x0f;
        int y0 = (int)y0f, x0 = (int)x0f;
        int   yy[2] = { y0, y0 + 1 };
        int   xx[2] = { x0, x0 + 1 };
        float wy[2] = { 1.f - fy, fy };
        float wx[2] = { 1.f - fx, fx };
        #pragma unroll
        for (int ii = 0; ii < 2; ii++)
            #pragma unroll
            for (int jj = 0; jj < 2; jj++) {
                int yi = yy[ii], xi = xx[jj];
                bool valid = (yi >= 0) && (yi < HH) && (xi >= 0) && (xi < WWID);
                int yc  = min(max(yi, 0), HH - 1);
                int xcc = min(max(xi, 0), WWID - 1);
                cidx[i * 4 + ii * 2 + jj] = yc * WWID + xcc;
                cwgt[i * 4 + ii * 2 + jj] = valid ? (wy[ii] * wx[jj] * m) : 0.f;
            }
    }

    // ---- A staging: 2048 chunks/kc, 4 per thread. advance +128 B per kc
    const char* ag[4]; int lo[4];
    #pragma unroll
    for (int i = 0; i < 4; i++) {
        int o = i * 512 + t;
        ag[i] = (const char*)wtb + (size_t)(o >> 3) * ROWB + (o & 7) * 16;
        lo[i] = o * 8;          // shorts (16 B per chunk)
    }

    // ---- sampling: thread -> (pixel spx, chunk sc); 8 lanes sweep 128 B
    int spx = t >> 3, sc = t & 7;
    const char* xb = (const char*)xh + (size_t)b * HWSZ * CIN * 2;
    int bofs = spx * 64 + (sc ^ (spx & 7)) * 8;   // Bs write offset (shorts)

    f32x4 acc[4][2];
    #pragma unroll
    for (int mi = 0; mi < 4; mi++)
        #pragma unroll
        for (int ni = 0; ni < 2; ni++) acc[mi][ni] = (f32x4)0.f;

    __syncthreads();   // coef + gs ready

    // prologue: issue gathers(0), A-glds(0)
    uint4 g[4]; float gw[4];
    {
        int cb = (spx * K2 + 0) * 4;
        #pragma unroll
        for (int c = 0; c < 4; c++) {
            gw[c] = cwgt[cb + c];
            g[c]  = *(const uint4*)(xb + (size_t)cidx[cb + c] * 512 + sc * 16);
        }
    }
    #pragma unroll
    for (int i = 0; i < 4; i++) GLOAD_LDS16(ag[i], &As[0][lo[i]]);

    for (int kc = 0; kc < NKC; kc++) {
        int cur = kc & 1;
        // ---- pack gathered corners -> Bs[cur]
        {
            float f[8] = {0,0,0,0,0,0,0,0};
            fma8(f, gw[0], g[0]); fma8(f, gw[1], g[1]);
            fma8(f, gw[2], g[2]); fma8(f, gw[3], g[3]);
            union { unsigned short s[8]; uint4 qq; } pk;
            #pragma unroll
            for (int e = 0; e < 8; e++) pk.s[e] = f2bf(f[e]);
            *(uint4*)&Bs[cur][bofs] = pk.qq;
        }
        __syncthreads();   // As[cur] staged (vmcnt) + Bs[cur] written (lgkm)

        if (kc < NKC - 1) {
            int kn = kc + 1;
            int k2n = kn >> 2, qn = kn & 3;
            int cb = (spx * K2 + k2n) * 4;
            #pragma unroll
            for (int c = 0; c < 4; c++) {
                gw[c] = cwgt[cb + c];
                g[c]  = *(const uint4*)(xb + (size_t)cidx[cb + c] * 512 + qn * 128 + sc * 16);
            }
            #pragma unroll
            for (int i = 0; i < 4; i++) {
                ag[i] += 128;
                GLOAD_LDS16(ag[i], &As[1 - cur][lo[i]]);
            }
        }

        // ---- MFMA on current buffers
        const unsigned short* Ap = As[cur];
        const unsigned short* Bp = Bs[cur];
        #pragma unroll
        for (int ks = 0; ks < 2; ks++) {
            int up = ((ks * 4 + half) ^ (r16 & 7)) * 8;
            bf16x8 af[4], bv[2];
            #pragma unroll
            for (int mi = 0; mi < 4; mi++)
                af[mi] = *(const bf16x8*)&Ap[(wm * 64 + mi * 16 + r16) * 64 + up];
            #pragma unroll
            for (int ni = 0; ni < 2; ni++)
                bv[ni] = *(const bf16x8*)&Bp[(wn * 32 + ni * 16 + r16) * 64 + up];
            #pragma unroll
            for (int mi = 0; mi < 4; mi++)
                #pragma unroll
                for (int ni = 0; ni < 2; ni++)
                    acc[mi][ni] = __builtin_amdgcn_mfma_f32_16x16x32_bf16(
                        af[mi], bv[ni], acc[mi][ni], 0, 0, 0);
        }
    }

    // ---- bias + GN partial stats (C/D: col=lane&15 -> n, row=half*4+reg -> m)
    float s4[4] = {0,0,0,0}, ss4[4] = {0,0,0,0};
    #pragma unroll
    for (int mi = 0; mi < 4; mi++) {
        #pragma unroll
        for (int r = 0; r < 4; r++) {
            float bs = bias[wm * 64 + mi * 16 + half * 4 + r];
            #pragma unroll
            for (int ni = 0; ni < 2; ni++) {
                float v = acc[mi][ni][r] + bs;
                acc[mi][ni][r] = v;
                s4[mi] += v; ss4[mi] += v * v;
            }
        }
    }
    #pragma unroll
    for (int mi = 0; mi < 4; mi++) {
        atomicAdd(&gs [wm * 8 + mi * 2 + gb], s4[mi]);
        atomicAdd(&gss[wm * 8 + mi * 2 + gb], ss4[mi]);
    }
    __syncthreads();
    if (t < 32) {
        atomicAdd(&gstat[(b * GROUPS + t) * 2 + 0], gs[t]);
        atomicAdd(&gstat[(b * GROUPS + t) * 2 + 1], gss[t]);
    }

    // ---- manual grid barrier (all 256 blocks resident: coop launch, 1/CU)
    if (t == 0) {
        __threadfence();
        atomicAdd(cnt, 1);
        while (__hip_atomic_load(cnt, __ATOMIC_ACQUIRE, __HIP_MEMORY_SCOPE_AGENT) < (int)gridDim.x)
            __builtin_amdgcn_s_sleep(4);
    }
    __syncthreads();

    const float inv = 1.f / (float)(CPG * HWSZ);
    if (t < 32) {
        float s  = aload(&gstat[(b * GROUPS + t) * 2 + 0]);
        float ss = aload(&gstat[(b * GROUPS + t) * 2 + 1]);
        float mu  = s * inv;
        float var = ss * inv - mu * mu;
        gmu[t]   = mu;
        grstd[t] = rsqrtf(var + EPSV);
    }
    __syncthreads();

    #pragma unroll
    for (int mi = 0; mi < 4; mi++) {
        int gl = wm * 8 + mi * 2 + gb;
        float mu = gmu[gl], rstd = grstd[gl];
        #pragma unroll
        for (int r = 0; r < 4; r++) {
            int co = wm * 64 + mi * 16 + half * 4 + r;
            float ga = gamma[co] * rstd;
            float be = beta[co] - mu * ga;
            float* orow = out + ((size_t)(b * COUT + co)) * HWSZ;
            #pragma unroll
            for (int ni = 0; ni < 2; ni++) {
                int n = hwbase + wn * 32 + ni * 16 + r16;
                orow[n] = fmaxf(acc[mi][ni][r] * ga + be, 0.f);
            }
        }
    }
}

// ---------------------------------------------------------------------------
extern "C" void kernel_launch(void* const* d_in, const int* in_sizes, int n_in,
                              void* d_out, int out_size, void* d_ws, size_t ws_size,
                              hipStream_t stream) {
    const float* x      = (const float*)d_in[0];
    const float* offset = (const float*)d_in[1];
    const float* mask   = (const float*)d_in[2];
    const float* weight = (const float*)d_in[3];
    const float* bias   = (const float*)d_in[4];
    const float* gamma  = (const float*)d_in[5];
    const float* beta   = (const float*)d_in[6];
    float* out = (float*)d_out;

    // workspace (~10 MB)
    unsigned short* xh    = (unsigned short*)d_ws;              // 4,194,304 us (8.4 MB)
    unsigned short* wtb   = xh + (size_t)4194304;               //   589,824 us (1.2 MB)
    float*          gstat = (float*)(wtb + (size_t)589824);     // 256 f + counter
    int*            cnt   = (int*)(gstat + 256);

    k_pre<<<dim3(129, 8, 4), 256, 0, stream>>>(x, xh, weight, wtb, gstat);

    const unsigned short* wtb_c = wtb; const unsigned short* xh_c = xh;
    void* args[] = { (void*)&wtb_c, (void*)&xh_c, (void*)&offset, (void*)&mask,
                     (void*)&bias, (void*)&gamma, (void*)&beta, (void*)&out,
                     (void*)&gstat, (void*)&cnt };
    hipLaunchCooperativeKernel((void*)k_mega, dim3(256), dim3(512), args, 0, stream);
}

// Round 9
// 151.316 us; speedup vs baseline: 1.2378x; 1.2378x over previous
//
#include <hip/hip_runtime.h>
#include <math.h>

// Problem constants
#define BB    4
#define CIN   256
#define HH    64
#define WWID  64
#define COUT  256
#define KKS   3
#define K2    9
#define PADV  1
#define HWSZ  4096
#define GROUPS 32
#define CPG   8
#define EPSV  1e-5f
#define ROWB  4608          // K2*CIN * sizeof(bf16)
#define NKC   36            // K chunks of 64

typedef __attribute__((ext_vector_type(8))) short bf16x8;
typedef __attribute__((ext_vector_type(4))) float f32x4;

#define GLOAD_LDS16(g, l) \
    __builtin_amdgcn_global_load_lds((const __attribute__((address_space(1))) unsigned int*)(g), \
                                     (__attribute__((address_space(3))) unsigned int*)(l), 16, 0, 0)

__device__ __forceinline__ unsigned short f2bf(float f) {
    unsigned u = __float_as_uint(f);
    u = (u + 0x7fffu + ((u >> 16) & 1u)) >> 16;   // RNE
    return (unsigned short)u;
}
__device__ __forceinline__ float bflo(unsigned q) { return __uint_as_float(q << 16); }
__device__ __forceinline__ float bfhi(unsigned q) { return __uint_as_float(q & 0xffff0000u); }
__device__ __forceinline__ void fma8(float* f, float w, uint4 q) {
    f[0] += w * bflo(q.x); f[1] += w * bfhi(q.x);
    f[2] += w * bflo(q.y); f[3] += w * bfhi(q.y);
    f[4] += w * bflo(q.z); f[5] += w * bfhi(q.z);
    f[6] += w * bflo(q.w); f[7] += w * bfhi(q.w);
}

// ---------------------------------------------------------------------------
// k_pre: grid (129, 8, 4).
//  bx<128 : x NCHW -> NHWC bf16 tile transpose
//  bx==128: weight [Cout][Cin][K2] -> bf16 [co][k2][q(64ch)][chunk c^(co&7)]
//           block (128,0,0) zeroes gstat (strided loop covers all 264)
// ---------------------------------------------------------------------------
__global__ __launch_bounds__(256)
void k_pre(const float* __restrict__ x, unsigned short* __restrict__ xh,
           const float* __restrict__ w, unsigned short* __restrict__ wtb,
           float* __restrict__ gstat) {
    int t = threadIdx.x;
    if (blockIdx.x < 128) {
        __shared__ float tile[32][33];
        int hw0 = blockIdx.x * 32;
        int c0  = blockIdx.y * 32;
        int b   = blockIdx.z;
        int tx = t & 31, ty = t >> 5;
        const float* xp = x + (size_t)b * CIN * HWSZ;
        #pragma unroll
        for (int i = 0; i < 4; i++)
            tile[ty + i * 8][tx] = xp[(c0 + ty + i * 8) * HWSZ + hw0 + tx];
        __syncthreads();
        int j = t >> 3, cq = t & 7;
        union { unsigned short s[4]; uint2 d; } pk;
        #pragma unroll
        for (int k = 0; k < 4; k++) pk.s[k] = f2bf(tile[cq * 4 + k][j]);
        *(uint2*)((char*)xh + ((size_t)b * HWSZ * CIN + (size_t)(hw0 + j) * CIN + c0 + cq * 4) * 2) = pk.d;
    } else {
        if (blockIdx.y == 0 && blockIdx.z == 0)
            for (int i = t; i < BB * GROUPS * 2 + 8; i += 256) gstat[i] = 0.f;
        int idx = (blockIdx.y * 4 + blockIdx.z) * 256 + t;   // [0,8192)
        int co = idx >> 5, c8 = idx & 31;
        int cin0 = c8 * 8;
        int q = c8 >> 3, c = c8 & 7;
        int pc = c ^ (co & 7);
        for (int k2 = 0; k2 < K2; k2++) {
            union { unsigned short s[8]; uint4 qq; } pk;
            #pragma unroll
            for (int j = 0; j < 8; j++)
                pk.s[j] = f2bf(w[(co * CIN + cin0 + j) * K2 + k2]);
            int phys = co * ROWB + k2 * 512 + q * 128 + pc * 16;
            *(uint4*)((char*)wtb + phys) = pk.qq;
        }
    }
}

// ---------------------------------------------------------------------------
// k_conv: fused-sampling implicit GEMM. 512 blocks x 256 thr, 3 blocks/CU.
// Per block: M=128 (mt half of couts) x N=64 px strip, K=2304 in 36 x BK=64.
// K-loop (m97 pattern): [A-glds(kc) + pack Bs(kc)] barrier
//                       [issue gathers(kc+1) (regs)] [MFMA(kc)] barrier.
// Linear-bid decode puts 32 contiguous strips x both m-halves on one XCD.
// Epilogue: bias + store + GN partial stats (block-LDS then global atomics).
// ---------------------------------------------------------------------------
__global__ __launch_bounds__(256)
void k_conv(const unsigned short* __restrict__ wtb, const unsigned short* __restrict__ xh,
            const float* __restrict__ offset, const float* __restrict__ mask,
            const float* __restrict__ bias, float* __restrict__ out,
            float* __restrict__ gstat) {
    __shared__ unsigned short As[128 * 64];   // 16 KB
    __shared__ unsigned short Bs[64 * 64];    // 8 KB
    __shared__ int   cidx[64 * K2 * 4];       // 9 KB
    __shared__ float cwgt[64 * K2 * 4];       // 9 KB
    __shared__ float gs[16], gss[16];

    // block decode: XCD k = bid&7 owns strips k*32..k*32+31, both m-halves
    int lid = blockIdx.x;
    int j8  = lid >> 3;
    int mt  = j8 & 1;
    int strip = (lid & 7) * 32 + (j8 >> 1);   // 0..255
    int b = strip >> 6;
    int hwbase = (strip & 63) * 64;
    int m0 = mt * 128;

    int t = threadIdx.x, w = t >> 6, l = t & 63;
    int r16 = l & 15, half = l >> 4;
    int wm = w & 1, wn = w >> 1;
    int skey = r16 & 7;

    if (t < 16) { gs[t] = 0.f; gss[t] = 0.f; }

    // ---- corner prep: 576 (px,k2) pairs
    for (int i = t; i < 64 * K2; i += 256) {
        int px = i / K2, k2 = i - px * K2;
        int hw = hwbase + px;
        int ho = hw >> 6, wo = hw & 63;
        int ky = k2 / KKS, kx = k2 - ky * KKS;
        float dy = offset[((b * (2 * K2) + k2 * 2 + 0) * HWSZ) + hw];
        float dx = offset[((b * (2 * K2) + k2 * 2 + 1) * HWSZ) + hw];
        float m  = mask[(b * K2 + k2) * HWSZ + hw];
        float y  = (float)(ky + ho - PADV) + dy;
        float xc = (float)(kx + wo - PADV) + dx;
        float y0f = floorf(y), x0f = floorf(xc);
        float fy = y - y0f, fx = xc - x0f;
        int y0 = (int)y0f, x0 = (int)x0f;
        int   yy[2] = { y0, y0 + 1 };
        int   xx[2] = { x0, x0 + 1 };
        float wy[2] = { 1.f - fy, fy };
        float wx[2] = { 1.f - fx, fx };
        #pragma unroll
        for (int ii = 0; ii < 2; ii++)
            #pragma unroll
            for (int jj = 0; jj < 2; jj++) {
                int yi = yy[ii], xi = xx[jj];
                bool valid = (yi >= 0) && (yi < HH) && (xi >= 0) && (xi < WWID);
                int yc  = min(max(yi, 0), HH - 1);
                int xcc = min(max(xi, 0), WWID - 1);
                cidx[i * 4 + ii * 2 + jj] = yc * WWID + xcc;
                cwgt[i * 4 + ii * 2 + jj] = valid ? (wy[ii] * wx[jj] * m) : 0.f;
            }
    }

    // ---- A staging: 1024 x 16B chunks per kc, 4/thread; +128 B per kc
    const char* ag[4]; unsigned short* lA[4];
    #pragma unroll
    for (int i = 0; i < 4; i++) {
        int o = i * 256 + t;
        ag[i] = (const char*)wtb + (size_t)(m0 + (o >> 3)) * ROWB + (o & 7) * 16;
        lA[i] = (unsigned short*)As + o * 8;
    }

    // ---- sampling mapping: 2 items/thread: (px = i*32 + t>>3, sc = t&7)
    int sc  = t & 7;
    int px0 = t >> 3;
    const char* xb = (const char*)xh + (size_t)b * HWSZ * CIN * 2;
    int bofs0 = px0 * 64 + (sc ^ (px0 & 7)) * 8;
    int px1 = px0 + 32;
    int bofs1 = px1 * 64 + (sc ^ (px1 & 7)) * 8;

    f32x4 acc[4][2];
    #pragma unroll
    for (int mi = 0; mi < 4; mi++)
        #pragma unroll
        for (int ni = 0; ni < 2; ni++) acc[mi][ni] = (f32x4)0.f;

    __syncthreads();   // coef + gs ready

    // prologue gathers for kc=0 (k2=0, q=0)
    uint4 g[2][4]; float gw[2][4];
    #pragma unroll
    for (int it = 0; it < 2; it++) {
        int cb = ((it ? px1 : px0) * K2) * 4;
        #pragma unroll
        for (int c = 0; c < 4; c++) {
            gw[it][c] = cwgt[cb + c];
            g[it][c]  = *(const uint4*)(xb + (size_t)cidx[cb + c] * 512 + sc * 16);
        }
    }

    for (int kc = 0; kc < NKC; kc++) {
        // A: async global->LDS (completes by the barrier)
        #pragma unroll
        for (int i = 0; i < 4; i++) { GLOAD_LDS16(ag[i], lA[i]); ag[i] += 128; }

        // pack gathered corners -> Bs
        #pragma unroll
        for (int it = 0; it < 2; it++) {
            float f[8] = {0,0,0,0,0,0,0,0};
            fma8(f, gw[it][0], g[it][0]); fma8(f, gw[it][1], g[it][1]);
            fma8(f, gw[it][2], g[it][2]); fma8(f, gw[it][3], g[it][3]);
            union { unsigned short s[8]; uint4 qq; } pk;
            #pragma unroll
            for (int e = 0; e < 8; e++) pk.s[e] = f2bf(f[e]);
            *(uint4*)&Bs[it ? bofs1 : bofs0] = pk.qq;
        }
        __syncthreads();   // As staged (vmcnt) + Bs written (lgkm)

        // prefetch gathers for kc+1 (register dest — fly during MFMA)
        if (kc < NKC - 1) {
            int kn = kc + 1;
            int k2n = kn >> 2, qn = kn & 3;
            #pragma unroll
            for (int it = 0; it < 2; it++) {
                int cb = ((it ? px1 : px0) * K2 + k2n) * 4;
                #pragma unroll
                for (int c = 0; c < 4; c++) {
                    gw[it][c] = cwgt[cb + c];
                    g[it][c]  = *(const uint4*)(xb + (size_t)cidx[cb + c] * 512 + qn * 128 + sc * 16);
                }
            }
        }

        // MFMA(kc)
        #pragma unroll
        for (int ks = 0; ks < 2; ks++) {
            int up = ((ks * 4 + half) ^ skey) * 8;
            bf16x8 af[4], bv[2];
            #pragma unroll
            for (int mi = 0; mi < 4; mi++)
                af[mi] = *(const bf16x8*)&As[(wm * 64 + mi * 16 + r16) * 64 + up];
            #pragma unroll
            for (int ni = 0; ni < 2; ni++)
                bv[ni] = *(const bf16x8*)&Bs[(wn * 32 + ni * 16 + r16) * 64 + up];
            #pragma unroll
            for (int mi = 0; mi < 4; mi++)
                #pragma unroll
                for (int ni = 0; ni < 2; ni++)
                    acc[mi][ni] = __builtin_amdgcn_mfma_f32_16x16x32_bf16(
                        af[mi], bv[ni], acc[mi][ni], 0, 0, 0);
        }
        __syncthreads();
    }

    // epilogue: bias + store + GN partials (C/D: col=lane&15 -> n, row=half*4+reg -> m)
    float s4[4] = {0,0,0,0}, ss4[4] = {0,0,0,0};
    #pragma unroll
    for (int mi = 0; mi < 4; mi++) {
        #pragma unroll
        for (int r = 0; r < 4; r++) {
            int co = m0 + wm * 64 + mi * 16 + half * 4 + r;
            float bs = bias[co];
            float* orow = out + ((size_t)(b * COUT + co)) * HWSZ;
            #pragma unroll
            for (int ni = 0; ni < 2; ni++) {
                int n = hwbase + wn * 32 + ni * 16 + r16;
                float v = acc[mi][ni][r] + bs;
                orow[n] = v;
                s4[mi] += v; ss4[mi] += v * v;
            }
        }
    }
    int gb = half >> 1;
    #pragma unroll
    for (int mi = 0; mi < 4; mi++) {
        atomicAdd(&gs [wm * 8 + mi * 2 + gb], s4[mi]);
        atomicAdd(&gss[wm * 8 + mi * 2 + gb], ss4[mi]);
    }
    __syncthreads();
    if (t < 16) {
        int gidx = (m0 >> 3) + t;
        atomicAdd(&gstat[(b * GROUPS + gidx) * 2 + 0], gs[t]);
        atomicAdd(&gstat[(b * GROUPS + gidx) * 2 + 1], gss[t]);
    }
}

// ---------------------------------------------------------------------------
// finalize: normalize + affine + ReLU in place (float4)
// ---------------------------------------------------------------------------
__global__ __launch_bounds__(256)
void k_gnfinal(float* __restrict__ out, const float* __restrict__ gstat,
               const float* __restrict__ gamma, const float* __restrict__ beta) {
    int i4 = blockIdx.x * 256 + threadIdx.x;
    int e  = i4 * 4;
    int c  = (e >> 12) & 255;
    int b  = e >> 20;
    int g  = c >> 3;
    float s  = gstat[((b * GROUPS) + g) * 2 + 0];
    float ss = gstat[((b * GROUPS) + g) * 2 + 1];
    const float inv = 1.f / (float)(CPG * HWSZ);
    float mu  = s * inv;
    float var = ss * inv - mu * mu;
    float rstd = rsqrtf(var + EPSV);
    float ga = gamma[c] * rstd;
    float be = beta[c] - mu * ga;
    float4 v = ((float4*)out)[i4];
    v.x = fmaxf(v.x * ga + be, 0.f);
    v.y = fmaxf(v.y * ga + be, 0.f);
    v.z = fmaxf(v.z * ga + be, 0.f);
    v.w = fmaxf(v.w * ga + be, 0.f);
    ((float4*)out)[i4] = v;
}

// ---------------------------------------------------------------------------
extern "C" void kernel_launch(void* const* d_in, const int* in_sizes, int n_in,
                              void* d_out, int out_size, void* d_ws, size_t ws_size,
                              hipStream_t stream) {
    const float* x      = (const float*)d_in[0];
    const float* offset = (const float*)d_in[1];
    const float* mask   = (const float*)d_in[2];
    const float* weight = (const float*)d_in[3];
    const float* bias   = (const float*)d_in[4];
    const float* gamma  = (const float*)d_in[5];
    const float* beta   = (const float*)d_in[6];
    float* out = (float*)d_out;

    // workspace (~10 MB)
    unsigned short* xh    = (unsigned short*)d_ws;              // 4,194,304 us (8.4 MB)
    unsigned short* wtb   = xh + (size_t)4194304;               //   589,824 us (1.2 MB)
    float*          gstat = (float*)(wtb + (size_t)589824);     // 264 f

    k_pre<<<dim3(129, 8, 4), 256, 0, stream>>>(x, xh, weight, wtb, gstat);
    k_conv<<<512, 256, 0, stream>>>(wtb, xh, offset, mask, bias, out, gstat);
    k_gnfinal<<<(size_t)BB * COUT * HWSZ / 1024, 256, 0, stream>>>(out, gstat, gamma, beta);
}